// Round 3
// baseline (122.055 us; speedup 1.0000x reference)
//
#include <hip/hip_runtime.h>
#include <math.h>

// AttentionContextEncoder on MI355X — R3: two-kernel split.
// K1: P[bn][h] = dot(e_bn, Wr[0:4,h])  (16 MB ws) + prop half of out.
// K2: rel half: x = (p_i + br) - p_j + w4*dist_ij; sum_j tanh(x).
//     p_j read as coalesced global dword (L1-resident per block);
//     LDS only 3 KB -> 16 blocks/CU, ~50 VGPR -> latency fully hidden.

#define NUM_ENT 64
#define DIM_ENT 4
#define HALF    128
#define BATCH   512
#define IPB     8                   // i's per K2 block
#define GPB     (NUM_ENT / IPB)     // 8 i-groups per batch

__device__ __forceinline__ float tanh5(float x) {
    float x2 = x * x;
    return x * fmaf(x2, fmaf(x2, 0.13333334f, -0.33333334f), 1.0f);
}

// ---- K1: per (b,n,h): p = e.Wr[0:4,h]; prop = tanh(e.Wp + bp). ----
__global__ __launch_bounds__(256) void k1_props(
    const float* __restrict__ ctx, const float* __restrict__ Wp,
    const float* __restrict__ bp,  const float* __restrict__ Wr,
    float* __restrict__ P, float* __restrict__ out)
{
    const int t  = blockIdx.x * 256 + threadIdx.x;
    const int bn = t >> 7;          // 0..32767 (wave-uniform)
    const int h  = t & 127;
    const int b  = bn >> 6, n = bn & 63;

    const float* c = ctx + (size_t)(n * 4) * BATCH + b;   // uniform -> s_load
    const float e0 = c[0], e1 = c[BATCH], e2 = c[2 * BATCH], e3 = c[3 * BATCH];

    // NOTE: identical fma chain to K2's a[] so the diagonal cancels to ~1ulp.
    float p = fmaf(e0, Wr[h], fmaf(e1, Wr[HALF + h],
              fmaf(e2, Wr[2 * HALF + h], e3 * Wr[3 * HALF + h])));
    P[(size_t)bn * HALF + h] = p;

    float xp = fmaf(e0, Wp[h], fmaf(e1, Wp[HALF + h],
               fmaf(e2, Wp[2 * HALF + h], fmaf(e3, Wp[3 * HALF + h], bp[h]))));
    out[(size_t)bn * (2 * HALF) + h] = tanh5(xp);
}

// ---- K2: relation sum for 8 i's per block. ----
__global__ __launch_bounds__(128, 4) void k2_rel(
    const float* __restrict__ ctx, const float* __restrict__ Wr,
    const float* __restrict__ br,  const float* __restrict__ P,
    float* __restrict__ out)
{
    __shared__ float4 se4[NUM_ENT];           // 1 KB
    __shared__ float  sdist[NUM_ENT * IPB];   // [j][ii], 2 KB

    const int bid  = blockIdx.x;
    const int b    = bid >> 3;                // GPB = 8
    const int base = (bid & (GPB - 1)) * IPB;
    const int h    = threadIdx.x;

    float* sef = (float*)se4;
    sef[h]       = ctx[(size_t)h * BATCH + b];
    sef[h + 128] = ctx[(size_t)(h + 128) * BATCH + b];
    __syncthreads();

    {   // dist tile: thread (ii = h&7, jg = h>>3) covers 4 j's.
        const int ii = h & (IPB - 1), jg = h >> 3;
        float4 ei = se4[base + ii];
        #pragma unroll
        for (int jj = 0; jj < 4; ++jj) {
            int j = jg * 4 + jj;
            float4 ej = se4[j];
            float d0 = ei.x - ej.x, d1 = ei.y - ej.y;
            sdist[j * IPB + ii] = sqrtf(fmaf(d0, d0, d1 * d1));  // 0 at j==i
        }
    }

    const float w0 = Wr[h],            w1 = Wr[HALF + h];
    const float w2 = Wr[2 * HALF + h], w3 = Wr[3 * HALF + h];
    const float w4 = Wr[4 * HALF + h];
    const float bb = br[h];

    float a[IPB], acc[IPB];
    #pragma unroll
    for (int ii = 0; ii < IPB; ++ii) {
        float4 e = se4[base + ii];
        a[ii] = fmaf(e.x, w0, fmaf(e.y, w1, fmaf(e.z, w2, e.w * w3))) + bb;
        acc[ii] = 0.0f;
    }
    __syncthreads();

    const float* Pb = P + (size_t)b * NUM_ENT * HALF + h;
    #pragma unroll 8
    for (int j = 0; j < NUM_ENT; ++j) {
        float pj = Pb[(size_t)j * HALF];          // coalesced, L1-resident
        float dj[IPB];
        const float4* dq = (const float4*)(sdist + j * IPB);
        *(float4*)(dj)     = dq[0];               // broadcast ds_read_b128
        *(float4*)(dj + 4) = dq[1];
        #pragma unroll
        for (int ii = 0; ii < IPB; ++ii) {
            float x  = fmaf(w4, dj[ii], a[ii] - pj);
            float x2 = x * x;
            acc[ii]  = fmaf(x, fmaf(x2, fmaf(x2, 0.13333334f, -0.33333334f),
                                    1.0f), acc[ii]);   // += tanh5(x)
        }
    }

    const float corr = tanh5(bb);                 // j==i term (x == bb ~1ulp)
    #pragma unroll
    for (int ii = 0; ii < IPB; ++ii) {
        out[(size_t)(b * NUM_ENT + base + ii) * (2 * HALF) + HALF + h] =
            acc[ii] - corr;
    }
}

extern "C" void kernel_launch(void* const* d_in, const int* in_sizes, int n_in,
                              void* d_out, int out_size, void* d_ws, size_t ws_size,
                              hipStream_t stream) {
    const float* ctx = (const float*)d_in[0];
    const float* Wp  = (const float*)d_in[1];
    const float* bp  = (const float*)d_in[2];
    const float* Wr  = (const float*)d_in[3];
    const float* br  = (const float*)d_in[4];
    float* out = (float*)d_out;
    float* P   = (float*)d_ws;   // 32768 * 128 * 4 B = 16 MB scratch

    k1_props<<<dim3(BATCH * NUM_ENT / 2), dim3(256), 0, stream>>>(
        ctx, Wp, bp, Wr, P, out);
    k2_rel<<<dim3(BATCH * GPB), dim3(HALF), 0, stream>>>(
        ctx, Wr, br, P, out);
}

// Round 4
// 114.284 us; speedup vs baseline: 1.0680x; 1.0680x over previous
//
#include <hip/hip_runtime.h>
#include <math.h>

// AttentionContextEncoder on MI355X — R4: scalar-pipe geometry + packed f32.
// All (b,i,j)-indexed data (entities, dists) is wave-uniform -> SGPRs via
// s_load; per-h weights in VGPRs; inner loop is v_pk_fma_f32 packed math.
// No LDS in the hot loop, no 16 MB P round-trip.

#define NUM_ENT 64
#define HALF    128
#define BATCH   512
#define IPB     16
#define GPB     (NUM_ENT / IPB)

typedef float v2f __attribute__((ext_vector_type(2)));

__device__ __forceinline__ float tanh5(float x) {
    float x2 = x * x;
    return x * fmaf(x2, fmaf(x2, 0.13333334f, -0.33333334f), 1.0f);
}

// ---- K0: transpose entities + all-pairs dist tiles into ws. ----
// entT: [b][n][4] (512 KB).  dist: [b][gi][j][ii] (8 MB), i = gi*16+ii.
__global__ __launch_bounds__(64) void k0_geom(const float* __restrict__ ctx,
                                              float* __restrict__ entT,
                                              float* __restrict__ dist)
{
    const int b = blockIdx.x, j = threadIdx.x;
    __shared__ float sx[NUM_ENT], sy[NUM_ENT];

    float e0 = ctx[(size_t)(j * 4 + 0) * BATCH + b];
    float e1 = ctx[(size_t)(j * 4 + 1) * BATCH + b];
    float e2 = ctx[(size_t)(j * 4 + 2) * BATCH + b];
    float e3 = ctx[(size_t)(j * 4 + 3) * BATCH + b];
    ((float4*)entT)[b * NUM_ENT + j] = make_float4(e0, e1, e2, e3);
    sx[j] = e0; sy[j] = e1;
    __syncthreads();

    float* drow = dist + (size_t)b * GPB * NUM_ENT * IPB + (size_t)j * IPB;
    #pragma unroll
    for (int gi = 0; gi < GPB; ++gi) {
        #pragma unroll
        for (int ii = 0; ii < IPB; ++ii) {
            int i = gi * IPB + ii;
            float dx = sx[i] - e0, dy = sy[i] - e1;
            drow[(size_t)gi * NUM_ENT * IPB + ii] =
                sqrtf(fmaf(dx, dx, dy * dy));        // exact 0 at i==j
        }
    }
}

// ---- K2: prop + relation sum; 16 i's per block, h = threadIdx. ----
__global__ __launch_bounds__(128) void k2_main(
    const float* __restrict__ entT, const float* __restrict__ dist,
    const float* __restrict__ Wp,   const float* __restrict__ bp,
    const float* __restrict__ Wr,   const float* __restrict__ br,
    float* __restrict__ out)
{
    const int b  = blockIdx.x >> 2;       // GPB = 4
    const int gi = blockIdx.x & (GPB - 1);
    const int h  = threadIdx.x;

    const float w0 = Wr[h],            w1 = Wr[HALF + h];
    const float w2 = Wr[2 * HALF + h], w3 = Wr[3 * HALF + h];
    const float w4 = Wr[4 * HALF + h];
    const float bb = br[h];
    const float q0 = Wp[h],            q1 = Wp[HALF + h];
    const float q2 = Wp[2 * HALF + h], q3 = Wp[3 * HALF + h];
    const float bq = bp[h];

    const float* eb = entT + ((size_t)b * NUM_ENT + gi * IPB) * 4; // uniform

    // a[ii] = p_i + bb; also emit the prop half (fused, e_i already scalar).
    v2f a2[IPB / 2];
    #pragma unroll
    for (int ii = 0; ii < IPB; ++ii) {
        float e0 = eb[ii * 4 + 0], e1 = eb[ii * 4 + 1];
        float e2 = eb[ii * 4 + 2], e3 = eb[ii * 4 + 3];
        float pi = fmaf(e0, w0, fmaf(e1, w1, fmaf(e2, w2, e3 * w3)));
        a2[ii >> 1][ii & 1] = pi + bb;
        float xp = fmaf(e0, q0, fmaf(e1, q1, fmaf(e2, q2, fmaf(e3, q3, bq))));
        out[(size_t)(b * NUM_ENT + gi * IPB + ii) * (2 * HALF) + h] = tanh5(xp);
    }

    v2f acc[IPB / 2];
    #pragma unroll
    for (int p = 0; p < IPB / 2; ++p) acc[p] = (v2f)(0.0f);

    const float* ejp = entT + (size_t)b * NUM_ENT * 4;               // uniform
    const float* dj  = dist + (size_t)(b * GPB + gi) * NUM_ENT * IPB; // uniform
    const v2f w4v = (v2f)(w4);
    const v2f C3v = (v2f)(-0.33333334f), C5v = (v2f)(0.13333334f);
    const v2f onev = (v2f)(1.0f);

    #pragma unroll 2
    for (int j = 0; j < NUM_ENT; ++j) {
        float f0 = ejp[j * 4 + 0], f1 = ejp[j * 4 + 1];  // s_load (uniform)
        float f2 = ejp[j * 4 + 2], f3 = ejp[j * 4 + 3];
        float pj = fmaf(f0, w0, fmaf(f1, w1, fmaf(f2, w2, f3 * w3)));
        v2f pjv = (v2f)(pj);
        const float* dr = dj + j * IPB;                   // s_load_dwordx16
        #pragma unroll
        for (int p = 0; p < IPB / 2; ++p) {
            v2f d;
            d.x = dr[2 * p]; d.y = dr[2 * p + 1];
            v2f x  = __builtin_elementwise_fma(w4v, d, a2[p] - pjv);
            v2f x2 = x * x;
            v2f t  = __builtin_elementwise_fma(x2, C5v, C3v);
            v2f r  = __builtin_elementwise_fma(x2, t, onev);
            acc[p] = __builtin_elementwise_fma(x, r, acc[p]); // += tanh5(x)
        }
    }

    // Diagonal removal: loop's j==i term is fma(w4,0,a-p_i) = a-p_i exactly,
    // with p_i from the identical fma chain -> exact cancel.
    #pragma unroll
    for (int ii = 0; ii < IPB; ++ii) {
        float e0 = eb[ii * 4 + 0], e1 = eb[ii * 4 + 1];
        float e2 = eb[ii * 4 + 2], e3 = eb[ii * 4 + 3];
        float pi = fmaf(e0, w0, fmaf(e1, w1, fmaf(e2, w2, e3 * w3)));
        float xd = a2[ii >> 1][ii & 1] - pi;
        float rel = acc[ii >> 1][ii & 1] - tanh5(xd);
        out[(size_t)(b * NUM_ENT + gi * IPB + ii) * (2 * HALF) + HALF + h] = rel;
    }
}

extern "C" void kernel_launch(void* const* d_in, const int* in_sizes, int n_in,
                              void* d_out, int out_size, void* d_ws, size_t ws_size,
                              hipStream_t stream) {
    const float* ctx = (const float*)d_in[0];
    const float* Wp  = (const float*)d_in[1];
    const float* bp  = (const float*)d_in[2];
    const float* Wr  = (const float*)d_in[3];
    const float* br  = (const float*)d_in[4];
    float* out  = (float*)d_out;
    float* entT = (float*)d_ws;                      // 512*64*4 floats
    float* dist = entT + (size_t)BATCH * NUM_ENT * 4; // 512*4*64*16 floats

    k0_geom<<<dim3(BATCH), dim3(NUM_ENT), 0, stream>>>(ctx, entT, dist);
    k2_main<<<dim3(BATCH * GPB), dim3(HALF), 0, stream>>>(
        entT, dist, Wp, bp, Wr, br, out);
}